// Round 13
// baseline (390.993 us; speedup 1.0000x reference)
//
#include <hip/hip_runtime.h>
#include <hip/hip_bf16.h>

// Problem: B=2,S=8192 -> TOK=16384 tokens; H=1024; DFF=4096.
// out[t] = mask[t] ? relu((h[t]*w[t]) @ W1 + b1) @ W2 + b2 : 0
// R17: split-K gemm2 REVERTED (R16: 107->122.6 — atomic RMW traffic +
//     doubled epilogue ate the TLP gain; MfmaUtil fell. gemm2 closed at
//     the R6 config, 8 variants tested). gemm1 RE-PORTED to the 8-phase
//     template with BOTH R8 bugs fixed: (1) BM=256xBN=128 -> 1152 active
//     blocks -> 4.5->5 rounds (+11% packing, was +33% at 256^2);
//     (2) ds_reads issued BEFORE the pre-MFMA barrier (m201 ordering) so
//     LDS latency overlaps the barrier wait instead of sitting on the
//     MFMA critical path. One vmcnt(0) per K-tile at P4 (6 stage loads
//     have ~3 phases to land). 512thr/8 waves (64x64 out each), 96 KiB
//     dbuf LDS (constructor attr — R8-proven safe). T1 XCD swizzle n-fast.

#define TOK 16384
#define HID 1024
#define FF  4096

typedef __attribute__((ext_vector_type(8))) __bf16 bf16x8;
typedef __attribute__((ext_vector_type(4))) float f32x4;

#define VMW(n) asm volatile("s_waitcnt vmcnt(" #n ")" ::: "memory")
#define CFENCE() asm volatile("" ::: "memory")

__device__ __forceinline__ void gload_lds16(const void* g, void* l) {
  // async global->LDS, 16B per lane; LDS dest = wave-uniform base + lane*16
  __builtin_amdgcn_global_load_lds((const __attribute__((address_space(1))) void*)g,
                                   (__attribute__((address_space(3))) void*)l, 16, 0, 0);
}

// ---------------- k_pre: W1^T + gate+compact (one dispatch) ----------------
// Blocks [0,1024): transpose W1 (64x64 tiles); [1024,2048): gate 16 tok/blk.
#define GTOK 16
#define NBT1 1024  // (FF/64)*(HID/64)

__global__ __launch_bounds__(256) void k_pre(const float* __restrict__ W1,
                                             __hip_bfloat16* __restrict__ W1t,
                                             const float* __restrict__ h,
                                             const float* __restrict__ wg,
                                             const float* __restrict__ bgp,
                                             const int* __restrict__ labels,
                                             float* __restrict__ out,
                                             __hip_bfloat16* __restrict__ A,
                                             int* __restrict__ idx,
                                             int* __restrict__ cnt) {
  const int bid = blockIdx.x;
  const int tid = threadIdx.x;

  if (bid < NBT1) {
    // -------- transpose W1[HID][FF] fp32 -> W1t[FF][HID] bf16 --------
    const int nbc = FF / 64;
    const int c0 = (bid % nbc) * 64, r0 = (bid / nbc) * 64;
    __shared__ float tile[64][65];        // stride 65: conflict-free col reads
    const int tx = tid & 63, ty = tid >> 6;
#pragma unroll
    for (int i = 0; i < 16; ++i)
      tile[ty + i * 4][tx] = W1[(size_t)(r0 + ty + i * 4) * FF + (c0 + tx)];
    __syncthreads();
#pragma unroll
    for (int i = 0; i < 16; ++i)
      W1t[(size_t)(c0 + ty + i * 4) * HID + (r0 + tx)] =
          __float2bfloat16(tile[tx][ty + i * 4]);
    return;
  }

  // -------- gate + compact + zero dropped rows --------
  const int gb = bid - NBT1;
  const int t0 = gb * GTOK;
  const int wave = tid >> 6, lane = tid & 63;

  float4 gv[4];
#pragma unroll
  for (int it = 0; it < 4; ++it) gv[it] = ((const float4*)wg)[it * 64 + lane];

  // hold h rows in registers across both passes (64 VGPR)
  float4 hv[4][4];
  __shared__ float slogit[GTOK];
  __shared__ int sslot[GTOK];

#pragma unroll
  for (int r = 0; r < 4; ++r) {
    const int li = r * 4 + wave;
    const float* hrow = h + (size_t)(t0 + li) * HID;
    float d = 0.f;
#pragma unroll
    for (int it = 0; it < 4; ++it) {
      hv[r][it] = ((const float4*)hrow)[it * 64 + lane];
      d += hv[r][it].x * gv[it].x + hv[r][it].y * gv[it].y +
           hv[r][it].z * gv[it].z + hv[r][it].w * gv[it].w;
    }
#pragma unroll
    for (int o = 32; o > 0; o >>= 1) d += __shfl_down(d, o, 64);
    if (lane == 0) slogit[li] = d;
  }
  __syncthreads();

  if (tid == 0) {  // prefix over 16 keep flags; ONE atomic per block
    const float bg = bgp[0];
    int slots[GTOK];
    int n = 0;
#pragma unroll
    for (int li = 0; li < GTOK; ++li) {
      const bool keep = (slogit[li] + bg >= 0.0f) || (labels[t0 + li] == -100);
      slots[li] = keep ? n++ : -1;
    }
    const int base = atomicAdd(cnt, n);
#pragma unroll
    for (int li = 0; li < GTOK; ++li)
      sslot[li] = slots[li] >= 0 ? base + slots[li] : -1;
  }
  __syncthreads();

#pragma unroll
  for (int r = 0; r < 4; ++r) {
    const int li = r * 4 + wave;
    const int t = t0 + li;
    const int m = sslot[li];
    if (m >= 0) {
      if (lane == 0) idx[m] = t;
      const float logit = slogit[li] + bgp[0];
      const float w = 1.0f / (1.0f + __expf(-logit));
#pragma unroll
      for (int it = 0; it < 4; ++it) {
        union { ushort4 u; __hip_bfloat16 b[4]; } pk;
        pk.b[0] = __float2bfloat16(hv[r][it].x * w);
        pk.b[1] = __float2bfloat16(hv[r][it].y * w);
        pk.b[2] = __float2bfloat16(hv[r][it].z * w);
        pk.b[3] = __float2bfloat16(hv[r][it].w * w);
        ((ushort4*)(A + (size_t)m * HID))[it * 64 + lane] = pk.u;
      }
    } else {
      const float4 z = make_float4(0.f, 0.f, 0.f, 0.f);
#pragma unroll
      for (int it = 0; it < 4; ++it)
        ((float4*)(out + (size_t)t * HID))[it * 64 + lane] = z;
    }
  }
}

// ---------------- GEMM LDS swizzle (both GEMMs) ----------------
// LDS rows of 64 k-elems (128 B). Staging: lane l covers row
// r = base + c*8 + (l>>3), source chunk g = (l&7) ^ (r&7), stored at
// position l&7. Read of chunk ck of row r at position ck ^ (r&7); fragment
// reads touch 16 rows x 4 chunks per instruction -> 2-way bank aliasing
// only (free; measured 0 conflicts).

// GEMM1: blocks [0,1024) transpose W2 (overlaps compute); blocks
// [1024,3072) = 256x128-tile 8-phase GEMM. 512 thr / 8 waves (4Mx2N,
// 64x64 out per wave), BK=64, 96 KiB dbuf LDS. Per K-tile: 4 phases
// {ds_read new frags; 2 stage calls; barrier; 8 MFMA; barrier}, quadrant
// order Q00,Q01,Q11,Q10 (b0 live across tile); single VMW(0) at P4
// validates next tile. T1: XCD-chunked, n-fast (A-tile 512KB L2-resident).
#define NBT2 1024  // (HID/64)*(FF/64)

__global__ __launch_bounds__(512, 2) void k_gemm1(const __hip_bfloat16* __restrict__ A,
                                                  const __hip_bfloat16* __restrict__ Bt,
                                                  const float* __restrict__ bias,
                                                  __hip_bfloat16* __restrict__ Act,
                                                  const int* __restrict__ cnt,
                                                  const float* __restrict__ W2,
                                                  __hip_bfloat16* __restrict__ W2t) {
  extern __shared__ char sm[];           // 2 x 48 KiB (A 32K | B 16K per buf)
  const int bid = blockIdx.x;
  const int tid = threadIdx.x;

  if (bid < NBT2) {
    // -------- transpose W2[FF][HID] fp32 -> W2t[HID][FF] bf16 --------
    float (*tile)[65] = (float(*)[65])sm;     // 64x65 fp32 = 16.6 KiB
    const int nbc = HID / 64;
    const int c0 = (bid % nbc) * 64, r0 = (bid / nbc) * 64;
    const int tx = tid & 63, ty = tid >> 6;   // ty 0..7 (512 thr)
#pragma unroll
    for (int i = 0; i < 8; ++i)
      tile[ty + i * 8][tx] = W2[(size_t)(r0 + ty + i * 8) * HID + (c0 + tx)];
    __syncthreads();
#pragma unroll
    for (int i = 0; i < 8; ++i)
      W2t[(size_t)(c0 + ty + i * 8) * FF + (r0 + tx)] =
          __float2bfloat16(tile[tx][ty + i * 8]);
    return;
  }

  // ---- T1 XCD-chunked decode (2048 gemm blocks = 8 XCDs x 8 mgrp x 32 n) ----
  const int g = bid - NBT2;              // 0..2047; 1024%8==0 keeps alignment
  const int xcd = g & 7;
  const int j = g >> 3;                  // 0..255
  const int mt = (j >> 5) * 8 + xcd;     // m-tile 0..63, ≡ xcd (mod 8)
  const int nt = j & 31;                 // n-fast: A-tile stays in XCD L2
  const int Mc = *cnt;
  const int m0 = mt * 256;
  if (m0 >= Mc) return;
  const int n0 = nt * 128;

  const int wid = tid >> 6, lane = tid & 63;
  const int wm = wid >> 1, wn = wid & 1;          // 4M x 2N wave grid
  const int fm = lane & 15, quad = lane >> 4;
  const int srow8 = lane >> 3;
  const int sg = ((lane & 7) ^ srow8) * 8;

  // staging: wave stages A rows [wid*32,+32) (4 calls), B rows [wid*16,+16) (2)
  const __hip_bfloat16* gA0 = A  + (size_t)(m0 + wid * 32 + srow8) * HID + sg;
  const __hip_bfloat16* gB0 = Bt + (size_t)(n0 + wid * 16 + srow8) * HID + sg;

  f32x4 acc[4][4] = {};

  auto stageA = [&](int nb, int c, int kt) {
    gload_lds16(gA0 + (size_t)(c * 8) * HID + kt,
                sm + nb * 49152 + wid * 4096 + c * 1024);
  };
  auto stageB = [&](int nb, int c, int kt) {
    gload_lds16(gB0 + (size_t)(c * 8) * HID + kt,
                sm + nb * 49152 + 32768 + wid * 2048 + c * 1024);
  };
  auto rdA = [&](int b, int h, bf16x8* a) {
    const __hip_bfloat16* p = (const __hip_bfloat16*)(sm + b * 49152);
#pragma unroll
    for (int f = 0; f < 2; ++f)
#pragma unroll
      for (int ks = 0; ks < 2; ++ks)
        a[f * 2 + ks] = *(const bf16x8*)&p[(wm * 64 + (h * 2 + f) * 16 + fm) * 64 +
                                           (((ks * 4 + quad) ^ (fm & 7)) * 8)];
  };
  auto rdB = [&](int b, int h, bf16x8* bb) {
    const __hip_bfloat16* p = (const __hip_bfloat16*)(sm + b * 49152 + 32768);
#pragma unroll
    for (int f = 0; f < 2; ++f)
#pragma unroll
      for (int ks = 0; ks < 2; ++ks)
        bb[f * 2 + ks] = *(const bf16x8*)&p[(wn * 64 + (h * 2 + f) * 16 + fm) * 64 +
                                            (((ks * 4 + quad) ^ (fm & 7)) * 8)];
  };
  auto mma8 = [&](const bf16x8* a, const bf16x8* bb, int mb, int nb2) {
    __builtin_amdgcn_s_setprio(1);
#pragma unroll
    for (int i2 = 0; i2 < 2; ++i2)
#pragma unroll
      for (int j2 = 0; j2 < 2; ++j2)
#pragma unroll
        for (int ks = 0; ks < 2; ++ks)
          acc[mb + i2][nb2 + j2] = __builtin_amdgcn_mfma_f32_16x16x32_bf16(
              a[i2 * 2 + ks], bb[j2 * 2 + ks], acc[mb + i2][nb2 + j2], 0, 0, 0);
    __builtin_amdgcn_s_setprio(0);
  };

  // prologue: tile 0 -> buf 0
#pragma unroll
  for (int c = 0; c < 4; ++c) stageA(0, c, 0);
#pragma unroll
  for (int c = 0; c < 2; ++c) stageB(0, c, 0);
  VMW(0);
  __builtin_amdgcn_s_barrier(); CFENCE();

  bf16x8 a0[4], a1[4], b0[4], b1[4];
  const int NT = HID / 64;   // 16
  for (int t = 0; t < NT; ++t) {
    const int buf = t & 1, nbuf = buf ^ 1;
    const bool pf = (t + 1) < NT;
    const int ktn = (t + 1) * 64;
    // P1: Q(0,0) — ds_reads BEFORE barrier (buf validated last tile)
    rdA(buf, 0, a0); rdB(buf, 0, b0);
    if (pf) { stageA(nbuf, 0, ktn); stageA(nbuf, 1, ktn); }
    __builtin_amdgcn_s_barrier(); CFENCE();
    mma8(a0, b0, 0, 0);
    __builtin_amdgcn_s_barrier(); CFENCE();
    // P2: Q(0,1)
    rdB(buf, 1, b1);
    if (pf) { stageA(nbuf, 2, ktn); stageA(nbuf, 3, ktn); }
    __builtin_amdgcn_s_barrier(); CFENCE();
    mma8(a0, b1, 0, 2);
    __builtin_amdgcn_s_barrier(); CFENCE();
    // P3: Q(1,1)
    rdA(buf, 1, a1);
    if (pf) { stageB(nbuf, 0, ktn); stageB(nbuf, 1, ktn); }
    __builtin_amdgcn_s_barrier(); CFENCE();
    mma8(a1, b1, 2, 2);
    __builtin_amdgcn_s_barrier(); CFENCE();
    // P4: Q(1,0) — a1,b0 live; drain this wave's 6 next-tile loads (had
    // ~3 phases to land), MFMA, then barrier => nbuf valid for t+1's P1.
    VMW(0);
    mma8(a1, b0, 2, 0);
    __builtin_amdgcn_s_barrier(); CFENCE();
  }

#pragma unroll
  for (int j2 = 0; j2 < 4; ++j2) {
    const int col = n0 + wn * 64 + j2 * 16 + fm;
    const float bv = bias[col];
#pragma unroll
    for (int i2 = 0; i2 < 4; ++i2) {
      const int rbase = m0 + wm * 64 + i2 * 16 + quad * 4;
#pragma unroll
      for (int r = 0; r < 4; ++r) {
        float v = acc[i2][j2][r] + bv;
        v = v > 0.f ? v : 0.f;
        Act[(size_t)(rbase + r) * FF + col] = __float2bfloat16(v);
      }
    }
  }
}

// GEMM2: out[idx[m]] = Act @ W2t^T + b2, fp32 scatter. K=FF=4096.
// EXACT R6 version (106.8us plateau; 8 variants measured, all worse):
// BM=64 x BN=128, 4 waves x (32x64), single-buffered, 24 KiB LDS.
__global__ __launch_bounds__(256, 4) void k_gemm2(const __hip_bfloat16* __restrict__ Act,
                                                  const __hip_bfloat16* __restrict__ Bt,
                                                  const float* __restrict__ bias,
                                                  const int* __restrict__ idx,
                                                  float* __restrict__ out,
                                                  const int* __restrict__ cnt) {
  const int Mc = *cnt;
  const int m0 = blockIdx.x * 64;
  if (m0 >= Mc) return;
  const int n0 = blockIdx.y * 128;

  __shared__ __hip_bfloat16 lA[64 * 64];   // 8 KiB
  __shared__ __hip_bfloat16 lB[128 * 64];  // 16 KiB

  const int tid = threadIdx.x;
  const int wave = tid >> 6, lane = tid & 63;
  const int wr = (wave >> 1) * 32, wc = (wave & 1) * 64;
  const int fm = lane & 15, quad = lane >> 4;
  const int srow = (lane >> 3);
  const int sg   = ((lane & 7) ^ srow) * 8;

  f32x4 acc[2][4] = {};

  const __hip_bfloat16* gA = Act + (size_t)(m0 + wave * 16 + srow) * FF + sg;
  const __hip_bfloat16* gB = Bt  + (size_t)(n0 + wave * 32 + srow) * FF + sg;
  char* dA = (char*)lA + wave * 2048;
  char* dB = (char*)lB + wave * 4096;

  for (int kt = 0; kt < FF; kt += 64) {
    __syncthreads();
#pragma unroll
    for (int c = 0; c < 2; ++c)
      gload_lds16(gA + (size_t)(c * 8) * FF + kt, dA + c * 1024);
#pragma unroll
    for (int c = 0; c < 4; ++c)
      gload_lds16(gB + (size_t)(c * 8) * FF + kt, dB + c * 1024);
    __syncthreads();
#pragma unroll
    for (int ks = 0; ks < 2; ++ks) {
      bf16x8 af[2], bb[4];
#pragma unroll
      for (int i = 0; i < 2; ++i)
        af[i] = *(const bf16x8*)&lA[(wr + i * 16 + fm) * 64 + (((ks * 4 + quad) ^ (fm & 7)) * 8)];
#pragma unroll
      for (int j = 0; j < 4; ++j)
        bb[j] = *(const bf16x8*)&lB[(wc + j * 16 + fm) * 64 + (((ks * 4 + quad) ^ (fm & 7)) * 8)];
#pragma unroll
      for (int i = 0; i < 2; ++i)
#pragma unroll
        for (int j = 0; j < 4; ++j)
          acc[i][j] = __builtin_amdgcn_mfma_f32_16x16x32_bf16(af[i], bb[j], acc[i][j], 0, 0, 0);
    }
  }

#pragma unroll
  for (int i = 0; i < 2; ++i) {
#pragma unroll
    for (int r = 0; r < 4; ++r) {
      const int m = m0 + wr + i * 16 + quad * 4 + r;
      if (m < Mc) {
        const int t = idx[m];
        float* orow = out + (size_t)t * HID + n0 + wc + fm;
#pragma unroll
        for (int j = 0; j < 4; ++j)
          orow[j * 16] = acc[i][j][r] + bias[n0 + wc + j * 16 + fm];
      }
    }
  }
}

// ---------------- one-time setup at library load (OUTSIDE graph capture) ----
__attribute__((constructor)) static void _athena_setup() {
  (void)hipFuncSetAttribute(reinterpret_cast<const void*>(k_gemm1),
                            hipFuncAttributeMaxDynamicSharedMemorySize, 98304);
}

// ---------------- launch ----------------
extern "C" void kernel_launch(void* const* d_in, const int* in_sizes, int n_in,
                              void* d_out, int out_size, void* d_ws, size_t ws_size,
                              hipStream_t stream) {
  const float* h   = (const float*)d_in[0];
  const float* Wg  = (const float*)d_in[3];
  const float* bg  = (const float*)d_in[4];
  const float* W1  = (const float*)d_in[5];
  const float* b1  = (const float*)d_in[6];
  const float* W2  = (const float*)d_in[7];
  const float* b2  = (const float*)d_in[8];
  const int*  labels = (const int*)d_in[9];
  float* out = (float*)d_out;

  char* ws = (char*)d_ws;
  int* cnt            = (int*)(ws + 0);
  int* idx            = (int*)(ws + 1024);
  __hip_bfloat16* W1t = (__hip_bfloat16*)(ws + (1u  << 17));   // [FF][HID]
  __hip_bfloat16* W2t = (__hip_bfloat16*)(ws + (16u << 20));   // [HID][FF]
  __hip_bfloat16* A   = (__hip_bfloat16*)(ws + (32u << 20));   // [TOK][HID]
  __hip_bfloat16* Act = (__hip_bfloat16*)(ws + (64ull << 20)); // [TOK][FF]

  hipMemsetAsync(cnt, 0, 4, stream);
  k_pre<<<NBT1 + TOK / GTOK, 256, 0, stream>>>(W1, W1t, h, Wg, bg, labels,
                                               out, A, idx, cnt);
  k_gemm1<<<NBT2 + (TOK / 256) * (FF / 128), 512, 98304, stream>>>(
      A, W1t, b1, Act, cnt, W2, W2t);
  k_gemm2<<<dim3(TOK / 64, HID / 128), 256, 0, stream>>>(Act, W2t, b2, idx, out, cnt);
}

// Round 14
// 369.078 us; speedup vs baseline: 1.0594x; 1.0594x over previous
//
#include <hip/hip_runtime.h>
#include <hip/hip_bf16.h>

// Problem: B=2,S=8192 -> TOK=16384 tokens; H=1024; DFF=4096.
// out[t] = mask[t] ? relu((h[t]*w[t]) @ W1 + b1) @ W2 + b2 : 0
// R18: 8-phase gemm1 REVERTED (R17: 98->137us — 96KiB LDS forces 1 block/CU
//     (2x96>160), VGPR=68 shows frags rematerialized; third 8-phase failure,
//     line closed). Back to R15 (362.6us best: R6 gemm structure + T1 on
//     gemm1 + W2t fold + fused pre). ONE change: gemm2 grid order m-fast ->
//     n-fast (x=n,y=m): 8 consecutive blocks (8 XCDs) share one 512KB Act
//     row-panel and W2t stays L3-resident -> FETCH ~193->~110MB expected.

#define TOK 16384
#define HID 1024
#define FF  4096

typedef __attribute__((ext_vector_type(8))) __bf16 bf16x8;
typedef __attribute__((ext_vector_type(4))) float f32x4;

__device__ __forceinline__ void gload_lds16(const void* g, void* l) {
  // async global->LDS, 16B per lane; LDS dest = wave-uniform base + lane*16
  __builtin_amdgcn_global_load_lds((const __attribute__((address_space(1))) void*)g,
                                   (__attribute__((address_space(3))) void*)l, 16, 0, 0);
}

// ---------------- k_pre: W1^T + gate+compact (one dispatch) ----------------
// Blocks [0,1024): transpose W1 (64x64 tiles); [1024,2048): gate 16 tok/blk.
#define GTOK 16
#define NBT1 1024  // (FF/64)*(HID/64)

__global__ __launch_bounds__(256) void k_pre(const float* __restrict__ W1,
                                             __hip_bfloat16* __restrict__ W1t,
                                             const float* __restrict__ h,
                                             const float* __restrict__ wg,
                                             const float* __restrict__ bgp,
                                             const int* __restrict__ labels,
                                             float* __restrict__ out,
                                             __hip_bfloat16* __restrict__ A,
                                             int* __restrict__ idx,
                                             int* __restrict__ cnt) {
  const int bid = blockIdx.x;
  const int tid = threadIdx.x;

  if (bid < NBT1) {
    // -------- transpose W1[HID][FF] fp32 -> W1t[FF][HID] bf16 --------
    const int nbc = FF / 64;
    const int c0 = (bid % nbc) * 64, r0 = (bid / nbc) * 64;
    __shared__ float tile[64][65];        // stride 65: conflict-free col reads
    const int tx = tid & 63, ty = tid >> 6;
#pragma unroll
    for (int i = 0; i < 16; ++i)
      tile[ty + i * 4][tx] = W1[(size_t)(r0 + ty + i * 4) * FF + (c0 + tx)];
    __syncthreads();
#pragma unroll
    for (int i = 0; i < 16; ++i)
      W1t[(size_t)(c0 + ty + i * 4) * HID + (r0 + tx)] =
          __float2bfloat16(tile[tx][ty + i * 4]);
    return;
  }

  // -------- gate + compact + zero dropped rows --------
  const int gb = bid - NBT1;
  const int t0 = gb * GTOK;
  const int wave = tid >> 6, lane = tid & 63;

  float4 gv[4];
#pragma unroll
  for (int it = 0; it < 4; ++it) gv[it] = ((const float4*)wg)[it * 64 + lane];

  // hold h rows in registers across both passes (64 VGPR)
  float4 hv[4][4];
  __shared__ float slogit[GTOK];
  __shared__ int sslot[GTOK];

#pragma unroll
  for (int r = 0; r < 4; ++r) {
    const int li = r * 4 + wave;
    const float* hrow = h + (size_t)(t0 + li) * HID;
    float d = 0.f;
#pragma unroll
    for (int it = 0; it < 4; ++it) {
      hv[r][it] = ((const float4*)hrow)[it * 64 + lane];
      d += hv[r][it].x * gv[it].x + hv[r][it].y * gv[it].y +
           hv[r][it].z * gv[it].z + hv[r][it].w * gv[it].w;
    }
#pragma unroll
    for (int o = 32; o > 0; o >>= 1) d += __shfl_down(d, o, 64);
    if (lane == 0) slogit[li] = d;
  }
  __syncthreads();

  if (tid == 0) {  // prefix over 16 keep flags; ONE atomic per block
    const float bg = bgp[0];
    int slots[GTOK];
    int n = 0;
#pragma unroll
    for (int li = 0; li < GTOK; ++li) {
      const bool keep = (slogit[li] + bg >= 0.0f) || (labels[t0 + li] == -100);
      slots[li] = keep ? n++ : -1;
    }
    const int base = atomicAdd(cnt, n);
#pragma unroll
    for (int li = 0; li < GTOK; ++li)
      sslot[li] = slots[li] >= 0 ? base + slots[li] : -1;
  }
  __syncthreads();

#pragma unroll
  for (int r = 0; r < 4; ++r) {
    const int li = r * 4 + wave;
    const int t = t0 + li;
    const int m = sslot[li];
    if (m >= 0) {
      if (lane == 0) idx[m] = t;
      const float logit = slogit[li] + bgp[0];
      const float w = 1.0f / (1.0f + __expf(-logit));
#pragma unroll
      for (int it = 0; it < 4; ++it) {
        union { ushort4 u; __hip_bfloat16 b[4]; } pk;
        pk.b[0] = __float2bfloat16(hv[r][it].x * w);
        pk.b[1] = __float2bfloat16(hv[r][it].y * w);
        pk.b[2] = __float2bfloat16(hv[r][it].z * w);
        pk.b[3] = __float2bfloat16(hv[r][it].w * w);
        ((ushort4*)(A + (size_t)m * HID))[it * 64 + lane] = pk.u;
      }
    } else {
      const float4 z = make_float4(0.f, 0.f, 0.f, 0.f);
#pragma unroll
      for (int it = 0; it < 4; ++it)
        ((float4*)(out + (size_t)t * HID))[it * 64 + lane] = z;
    }
  }
}

// ---------------- GEMM LDS swizzle (both GEMMs) ----------------
// LDS rows of 64 k-elems (128 B). Staging: lane l covers row
// r = wbase + c*8 + (l>>3), source chunk g = (l&7) ^ (r&7), stored at
// position l&7. Read of chunk ck of row r at position ck ^ (r&7); fragment
// reads touch 16 rows x 4 chunks per instruction -> 2-way bank aliasing
// only (free; measured 0 conflicts). NOTE: 32x32 MFMA layout (32 rows x
// 2 chunks) is 4-way conflicted in this scheme — do not use (R12).

// GEMM1 dispatch: blocks [0,1024) transpose W2[FF][HID]->W2t[HID][FF]
// (overlaps with gemm compute); blocks [1024,5120) = 128x128-tile GEMM,
// single-buffered, XCD-chunk-swizzled (T1, R15: +3us).
#define NBT2 1024  // (HID/64)*(FF/64)

__global__ __launch_bounds__(256, 2) void k_gemm1(const __hip_bfloat16* __restrict__ A,
                                                  const __hip_bfloat16* __restrict__ Bt,
                                                  const float* __restrict__ bias,
                                                  __hip_bfloat16* __restrict__ Act,
                                                  const int* __restrict__ cnt,
                                                  const float* __restrict__ W2,
                                                  __hip_bfloat16* __restrict__ W2t) {
  __shared__ char smem[32768];           // union: gemm lA|lB, transpose tile
  const int bid = blockIdx.x;
  const int tid = threadIdx.x;

  if (bid < NBT2) {
    // -------- transpose W2[FF][HID] fp32 -> W2t[HID][FF] bf16 --------
    float (*tile)[65] = (float(*)[65])smem;   // 64x65 fp32 = 16.25 KiB
    const int nbc = HID / 64;
    const int c0 = (bid % nbc) * 64, r0 = (bid / nbc) * 64;
    const int tx = tid & 63, ty = tid >> 6;
#pragma unroll
    for (int i = 0; i < 16; ++i)
      tile[ty + i * 4][tx] = W2[(size_t)(r0 + ty + i * 4) * HID + (c0 + tx)];
    __syncthreads();
#pragma unroll
    for (int i = 0; i < 16; ++i)
      W2t[(size_t)(c0 + ty + i * 4) * FF + (r0 + tx)] =
          __float2bfloat16(tile[tx][ty + i * 4]);
    return;
  }

  // ---- T1 XCD-chunked decode (bijective: 4096 = 8 XCDs x 512) ----
  const int g = bid - NBT2;              // 0..4095; bid%8 alignment: 1024%8==0
  const int xcd = g & 7;
  const int j = g >> 3;                  // 0..511
  const int mt = (j & 15) * 8 + xcd;     // m-tile 0..127, ≡ xcd (mod 8)
  const int nt = j >> 4;                 // n-tile 0..31
  const int Mc = *cnt;
  const int m0 = mt * 128;
  if (m0 >= Mc) return;
  const int n0 = nt * 128;

  __hip_bfloat16* lA = (__hip_bfloat16*)smem;            // 16 KiB
  __hip_bfloat16* lB = (__hip_bfloat16*)(smem + 16384);  // 16 KiB

  const int wave = tid >> 6, lane = tid & 63;
  const int wr = (wave >> 1) * 64, wc = (wave & 1) * 64;
  const int fm = lane & 15, quad = lane >> 4;

  const int srow = (lane >> 3);                       // 0..7
  const int sg   = ((lane & 7) ^ srow) * 8;           // global elem offset

  f32x4 acc[4][4] = {};

  const __hip_bfloat16* gA = A  + (size_t)(m0 + wave * 32 + srow) * HID + sg;
  const __hip_bfloat16* gB = Bt + (size_t)(n0 + wave * 32 + srow) * HID + sg;
  char* dA = (char*)lA + wave * 4096;
  char* dB = (char*)lB + wave * 4096;

  for (int kt = 0; kt < HID; kt += 64) {
    __syncthreads();
#pragma unroll
    for (int c = 0; c < 4; ++c) {
      gload_lds16(gA + (size_t)(c * 8) * HID + kt, dA + c * 1024);
      gload_lds16(gB + (size_t)(c * 8) * HID + kt, dB + c * 1024);
    }
    __syncthreads();
#pragma unroll
    for (int ks = 0; ks < 2; ++ks) {
      bf16x8 af[4], bb[4];
#pragma unroll
      for (int i = 0; i < 4; ++i)
        af[i] = *(const bf16x8*)&lA[(wr + i * 16 + fm) * 64 + (((ks * 4 + quad) ^ (fm & 7)) * 8)];
#pragma unroll
      for (int j2 = 0; j2 < 4; ++j2)
        bb[j2] = *(const bf16x8*)&lB[(wc + j2 * 16 + fm) * 64 + (((ks * 4 + quad) ^ (fm & 7)) * 8)];
#pragma unroll
      for (int i = 0; i < 4; ++i)
#pragma unroll
        for (int j2 = 0; j2 < 4; ++j2)
          acc[i][j2] = __builtin_amdgcn_mfma_f32_16x16x32_bf16(af[i], bb[j2], acc[i][j2], 0, 0, 0);
    }
  }

#pragma unroll
  for (int j2 = 0; j2 < 4; ++j2) {
    const int col = n0 + wc + j2 * 16 + fm;
    const float bv = bias[col];
#pragma unroll
    for (int i = 0; i < 4; ++i) {
      const int rbase = m0 + wr + i * 16 + quad * 4;
#pragma unroll
      for (int r = 0; r < 4; ++r) {
        float v = acc[i][j2][r] + bv;
        v = v > 0.f ? v : 0.f;
        Act[(size_t)(rbase + r) * FF + col] = __float2bfloat16(v);
      }
    }
  }
}

// GEMM2: out[idx[m]] = Act @ W2t^T + b2, fp32 scatter. K=FF=4096.
// R6 plateau geometry (BM=64 x BN=128, 4 waves x (32x64), single-buffered,
// 24 KiB LDS) with N-FAST grid order: blockIdx.x = n-tile (8), .y = m-tile
// (256). 8 consecutive blocks (-> 8 XCDs) share one 512KB Act row-panel
// (read ~once from L3) and W2t (8MB) stays L3-resident across m-groups.
__global__ __launch_bounds__(256, 4) void k_gemm2(const __hip_bfloat16* __restrict__ Act,
                                                  const __hip_bfloat16* __restrict__ Bt,
                                                  const float* __restrict__ bias,
                                                  const int* __restrict__ idx,
                                                  float* __restrict__ out,
                                                  const int* __restrict__ cnt) {
  const int Mc = *cnt;
  const int m0 = blockIdx.y * 64;        // n-fast: y is m-tile
  if (m0 >= Mc) return;
  const int n0 = blockIdx.x * 128;       // x is n-tile (8 of them)

  __shared__ __hip_bfloat16 lA[64 * 64];   // 8 KiB
  __shared__ __hip_bfloat16 lB[128 * 64];  // 16 KiB

  const int tid = threadIdx.x;
  const int wave = tid >> 6, lane = tid & 63;
  const int wr = (wave >> 1) * 32, wc = (wave & 1) * 64;
  const int fm = lane & 15, quad = lane >> 4;
  const int srow = (lane >> 3);
  const int sg   = ((lane & 7) ^ srow) * 8;

  f32x4 acc[2][4] = {};

  const __hip_bfloat16* gA = Act + (size_t)(m0 + wave * 16 + srow) * FF + sg;
  const __hip_bfloat16* gB = Bt  + (size_t)(n0 + wave * 32 + srow) * FF + sg;
  char* dA = (char*)lA + wave * 2048;
  char* dB = (char*)lB + wave * 4096;

  for (int kt = 0; kt < FF; kt += 64) {
    __syncthreads();
#pragma unroll
    for (int c = 0; c < 2; ++c)
      gload_lds16(gA + (size_t)(c * 8) * FF + kt, dA + c * 1024);
#pragma unroll
    for (int c = 0; c < 4; ++c)
      gload_lds16(gB + (size_t)(c * 8) * FF + kt, dB + c * 1024);
    __syncthreads();
#pragma unroll
    for (int ks = 0; ks < 2; ++ks) {
      bf16x8 af[2], bb[4];
#pragma unroll
      for (int i = 0; i < 2; ++i)
        af[i] = *(const bf16x8*)&lA[(wr + i * 16 + fm) * 64 + (((ks * 4 + quad) ^ (fm & 7)) * 8)];
#pragma unroll
      for (int j = 0; j < 4; ++j)
        bb[j] = *(const bf16x8*)&lB[(wc + j * 16 + fm) * 64 + (((ks * 4 + quad) ^ (fm & 7)) * 8)];
#pragma unroll
      for (int i = 0; i < 2; ++i)
#pragma unroll
        for (int j = 0; j < 4; ++j)
          acc[i][j] = __builtin_amdgcn_mfma_f32_16x16x32_bf16(af[i], bb[j], acc[i][j], 0, 0, 0);
    }
  }

#pragma unroll
  for (int i = 0; i < 2; ++i) {
#pragma unroll
    for (int r = 0; r < 4; ++r) {
      const int m = m0 + wr + i * 16 + quad * 4 + r;
      if (m < Mc) {
        const int t = idx[m];
        float* orow = out + (size_t)t * HID + n0 + wc + fm;
#pragma unroll
        for (int j = 0; j < 4; ++j)
          orow[j * 16] = acc[i][j][r] + bias[n0 + wc + j * 16 + fm];
      }
    }
  }
}

// ---------------- launch ----------------
extern "C" void kernel_launch(void* const* d_in, const int* in_sizes, int n_in,
                              void* d_out, int out_size, void* d_ws, size_t ws_size,
                              hipStream_t stream) {
  const float* h   = (const float*)d_in[0];
  const float* Wg  = (const float*)d_in[3];
  const float* bg  = (const float*)d_in[4];
  const float* W1  = (const float*)d_in[5];
  const float* b1  = (const float*)d_in[6];
  const float* W2  = (const float*)d_in[7];
  const float* b2  = (const float*)d_in[8];
  const int*  labels = (const int*)d_in[9];
  float* out = (float*)d_out;

  char* ws = (char*)d_ws;
  int* cnt            = (int*)(ws + 0);
  int* idx            = (int*)(ws + 1024);
  __hip_bfloat16* W1t = (__hip_bfloat16*)(ws + (1u  << 17));   // [FF][HID]
  __hip_bfloat16* W2t = (__hip_bfloat16*)(ws + (16u << 20));   // [HID][FF]
  __hip_bfloat16* A   = (__hip_bfloat16*)(ws + (32u << 20));   // [TOK][HID]
  __hip_bfloat16* Act = (__hip_bfloat16*)(ws + (64ull << 20)); // [TOK][FF]

  hipMemsetAsync(cnt, 0, 4, stream);
  k_pre<<<NBT1 + TOK / GTOK, 256, 0, stream>>>(W1, W1t, h, Wg, bg, labels,
                                               out, A, idx, cnt);
  k_gemm1<<<NBT2 + (TOK / 128) * (FF / 128), 256, 0, stream>>>(A, W1t, b1, Act,
                                                               cnt, W2, W2t);
  k_gemm2<<<dim3(HID / 128, TOK / 64), 256, 0, stream>>>(Act, W2t, b2, idx, out, cnt);
}

// Round 15
// 360.941 us; speedup vs baseline: 1.0833x; 1.0225x over previous
//
#include <hip/hip_runtime.h>
#include <hip/hip_bf16.h>

// Problem: B=2,S=8192 -> TOK=16384 tokens; H=1024; DFF=4096.
// out[t] = mask[t] ? relu((h[t]*w[t]) @ W1 + b1) @ W2 + b2 : 0
// R19 (FINAL): n-fast gemm2 REVERTED (R18: FETCH 193->300MB, 107->112us —
//     both grid-order theories falsified; gemm2 is latency-bound at its
//     structural plateau, 2.1TB/s = 34% of achievable BW). This is R15
//     exactly — the measured best (362.6us):
//     - k_pre: W1^T + gate fused, one atomicAdd/16 tokens, h in regs
//     - k_gemm1: 128^2 2-barrier + T1 XCD-chunked swizzle + W2^T folded in
//     - k_gemm2: 64x128 4-wave single-buffer m-fast (10 variants, all worse)
//     Ceiling: both GEMMs at 75-85% of the ~900TF 2-barrier structure
//     ceiling; 8-phase path failed 3x on packing/occupancy at these shapes;
//     ~130us of wall is fixed harness reset overhead.

#define TOK 16384
#define HID 1024
#define FF  4096

typedef __attribute__((ext_vector_type(8))) __bf16 bf16x8;
typedef __attribute__((ext_vector_type(4))) float f32x4;

__device__ __forceinline__ void gload_lds16(const void* g, void* l) {
  // async global->LDS, 16B per lane; LDS dest = wave-uniform base + lane*16
  __builtin_amdgcn_global_load_lds((const __attribute__((address_space(1))) void*)g,
                                   (__attribute__((address_space(3))) void*)l, 16, 0, 0);
}

// ---------------- k_pre: W1^T + gate+compact (one dispatch) ----------------
// Blocks [0,1024): transpose W1 (64x64 tiles); [1024,2048): gate 16 tok/blk.
#define GTOK 16
#define NBT1 1024  // (FF/64)*(HID/64)

__global__ __launch_bounds__(256) void k_pre(const float* __restrict__ W1,
                                             __hip_bfloat16* __restrict__ W1t,
                                             const float* __restrict__ h,
                                             const float* __restrict__ wg,
                                             const float* __restrict__ bgp,
                                             const int* __restrict__ labels,
                                             float* __restrict__ out,
                                             __hip_bfloat16* __restrict__ A,
                                             int* __restrict__ idx,
                                             int* __restrict__ cnt) {
  const int bid = blockIdx.x;
  const int tid = threadIdx.x;

  if (bid < NBT1) {
    // -------- transpose W1[HID][FF] fp32 -> W1t[FF][HID] bf16 --------
    const int nbc = FF / 64;
    const int c0 = (bid % nbc) * 64, r0 = (bid / nbc) * 64;
    __shared__ float tile[64][65];        // stride 65: conflict-free col reads
    const int tx = tid & 63, ty = tid >> 6;
#pragma unroll
    for (int i = 0; i < 16; ++i)
      tile[ty + i * 4][tx] = W1[(size_t)(r0 + ty + i * 4) * FF + (c0 + tx)];
    __syncthreads();
#pragma unroll
    for (int i = 0; i < 16; ++i)
      W1t[(size_t)(c0 + ty + i * 4) * HID + (r0 + tx)] =
          __float2bfloat16(tile[tx][ty + i * 4]);
    return;
  }

  // -------- gate + compact + zero dropped rows --------
  const int gb = bid - NBT1;
  const int t0 = gb * GTOK;
  const int wave = tid >> 6, lane = tid & 63;

  float4 gv[4];
#pragma unroll
  for (int it = 0; it < 4; ++it) gv[it] = ((const float4*)wg)[it * 64 + lane];

  // hold h rows in registers across both passes (64 VGPR)
  float4 hv[4][4];
  __shared__ float slogit[GTOK];
  __shared__ int sslot[GTOK];

#pragma unroll
  for (int r = 0; r < 4; ++r) {
    const int li = r * 4 + wave;
    const float* hrow = h + (size_t)(t0 + li) * HID;
    float d = 0.f;
#pragma unroll
    for (int it = 0; it < 4; ++it) {
      hv[r][it] = ((const float4*)hrow)[it * 64 + lane];
      d += hv[r][it].x * gv[it].x + hv[r][it].y * gv[it].y +
           hv[r][it].z * gv[it].z + hv[r][it].w * gv[it].w;
    }
#pragma unroll
    for (int o = 32; o > 0; o >>= 1) d += __shfl_down(d, o, 64);
    if (lane == 0) slogit[li] = d;
  }
  __syncthreads();

  if (tid == 0) {  // prefix over 16 keep flags; ONE atomic per block
    const float bg = bgp[0];
    int slots[GTOK];
    int n = 0;
#pragma unroll
    for (int li = 0; li < GTOK; ++li) {
      const bool keep = (slogit[li] + bg >= 0.0f) || (labels[t0 + li] == -100);
      slots[li] = keep ? n++ : -1;
    }
    const int base = atomicAdd(cnt, n);
#pragma unroll
    for (int li = 0; li < GTOK; ++li)
      sslot[li] = slots[li] >= 0 ? base + slots[li] : -1;
  }
  __syncthreads();

#pragma unroll
  for (int r = 0; r < 4; ++r) {
    const int li = r * 4 + wave;
    const int t = t0 + li;
    const int m = sslot[li];
    if (m >= 0) {
      if (lane == 0) idx[m] = t;
      const float logit = slogit[li] + bgp[0];
      const float w = 1.0f / (1.0f + __expf(-logit));
#pragma unroll
      for (int it = 0; it < 4; ++it) {
        union { ushort4 u; __hip_bfloat16 b[4]; } pk;
        pk.b[0] = __float2bfloat16(hv[r][it].x * w);
        pk.b[1] = __float2bfloat16(hv[r][it].y * w);
        pk.b[2] = __float2bfloat16(hv[r][it].z * w);
        pk.b[3] = __float2bfloat16(hv[r][it].w * w);
        ((ushort4*)(A + (size_t)m * HID))[it * 64 + lane] = pk.u;
      }
    } else {
      const float4 z = make_float4(0.f, 0.f, 0.f, 0.f);
#pragma unroll
      for (int it = 0; it < 4; ++it)
        ((float4*)(out + (size_t)t * HID))[it * 64 + lane] = z;
    }
  }
}

// ---------------- GEMM LDS swizzle (both GEMMs) ----------------
// LDS rows of 64 k-elems (128 B). Staging: lane l covers row
// r = wbase + c*8 + (l>>3), source chunk g = (l&7) ^ (r&7), stored at
// position l&7. Read of chunk ck of row r at position ck ^ (r&7); fragment
// reads touch 16 rows x 4 chunks per instruction -> 2-way bank aliasing
// only (free; measured 0 conflicts). NOTE: 32x32 MFMA layout (32 rows x
// 2 chunks) is 4-way conflicted in this scheme — do not use (R12).

// GEMM1 dispatch: blocks [0,1024) transpose W2[FF][HID]->W2t[HID][FF]
// (overlaps with gemm compute); blocks [1024,5120) = 128x128-tile GEMM,
// single-buffered, XCD-chunk-swizzled (T1, R15: +3us).
#define NBT2 1024  // (HID/64)*(FF/64)

__global__ __launch_bounds__(256, 2) void k_gemm1(const __hip_bfloat16* __restrict__ A,
                                                  const __hip_bfloat16* __restrict__ Bt,
                                                  const float* __restrict__ bias,
                                                  __hip_bfloat16* __restrict__ Act,
                                                  const int* __restrict__ cnt,
                                                  const float* __restrict__ W2,
                                                  __hip_bfloat16* __restrict__ W2t) {
  __shared__ char smem[32768];           // union: gemm lA|lB, transpose tile
  const int bid = blockIdx.x;
  const int tid = threadIdx.x;

  if (bid < NBT2) {
    // -------- transpose W2[FF][HID] fp32 -> W2t[HID][FF] bf16 --------
    float (*tile)[65] = (float(*)[65])smem;   // 64x65 fp32 = 16.25 KiB
    const int nbc = HID / 64;
    const int c0 = (bid % nbc) * 64, r0 = (bid / nbc) * 64;
    const int tx = tid & 63, ty = tid >> 6;
#pragma unroll
    for (int i = 0; i < 16; ++i)
      tile[ty + i * 4][tx] = W2[(size_t)(r0 + ty + i * 4) * HID + (c0 + tx)];
    __syncthreads();
#pragma unroll
    for (int i = 0; i < 16; ++i)
      W2t[(size_t)(c0 + ty + i * 4) * FF + (r0 + tx)] =
          __float2bfloat16(tile[tx][ty + i * 4]);
    return;
  }

  // ---- T1 XCD-chunked decode (bijective: 4096 = 8 XCDs x 512) ----
  const int g = bid - NBT2;              // 0..4095; bid%8 alignment: 1024%8==0
  const int xcd = g & 7;
  const int j = g >> 3;                  // 0..511
  const int mt = (j & 15) * 8 + xcd;     // m-tile 0..127, ≡ xcd (mod 8)
  const int nt = j >> 4;                 // n-tile 0..31
  const int Mc = *cnt;
  const int m0 = mt * 128;
  if (m0 >= Mc) return;
  const int n0 = nt * 128;

  __hip_bfloat16* lA = (__hip_bfloat16*)smem;            // 16 KiB
  __hip_bfloat16* lB = (__hip_bfloat16*)(smem + 16384);  // 16 KiB

  const int wave = tid >> 6, lane = tid & 63;
  const int wr = (wave >> 1) * 64, wc = (wave & 1) * 64;
  const int fm = lane & 15, quad = lane >> 4;

  const int srow = (lane >> 3);                       // 0..7
  const int sg   = ((lane & 7) ^ srow) * 8;           // global elem offset

  f32x4 acc[4][4] = {};

  const __hip_bfloat16* gA = A  + (size_t)(m0 + wave * 32 + srow) * HID + sg;
  const __hip_bfloat16* gB = Bt + (size_t)(n0 + wave * 32 + srow) * HID + sg;
  char* dA = (char*)lA + wave * 4096;
  char* dB = (char*)lB + wave * 4096;

  for (int kt = 0; kt < HID; kt += 64) {
    __syncthreads();
#pragma unroll
    for (int c = 0; c < 4; ++c) {
      gload_lds16(gA + (size_t)(c * 8) * HID + kt, dA + c * 1024);
      gload_lds16(gB + (size_t)(c * 8) * HID + kt, dB + c * 1024);
    }
    __syncthreads();
#pragma unroll
    for (int ks = 0; ks < 2; ++ks) {
      bf16x8 af[4], bb[4];
#pragma unroll
      for (int i = 0; i < 4; ++i)
        af[i] = *(const bf16x8*)&lA[(wr + i * 16 + fm) * 64 + (((ks * 4 + quad) ^ (fm & 7)) * 8)];
#pragma unroll
      for (int j2 = 0; j2 < 4; ++j2)
        bb[j2] = *(const bf16x8*)&lB[(wc + j2 * 16 + fm) * 64 + (((ks * 4 + quad) ^ (fm & 7)) * 8)];
#pragma unroll
      for (int i = 0; i < 4; ++i)
#pragma unroll
        for (int j2 = 0; j2 < 4; ++j2)
          acc[i][j2] = __builtin_amdgcn_mfma_f32_16x16x32_bf16(af[i], bb[j2], acc[i][j2], 0, 0, 0);
    }
  }

#pragma unroll
  for (int j2 = 0; j2 < 4; ++j2) {
    const int col = n0 + wc + j2 * 16 + fm;
    const float bv = bias[col];
#pragma unroll
    for (int i = 0; i < 4; ++i) {
      const int rbase = m0 + wr + i * 16 + quad * 4;
#pragma unroll
      for (int r = 0; r < 4; ++r) {
        float v = acc[i][j2][r] + bv;
        v = v > 0.f ? v : 0.f;
        Act[(size_t)(rbase + r) * FF + col] = __float2bfloat16(v);
      }
    }
  }
}

// GEMM2: out[idx[m]] = Act @ W2t^T + b2, fp32 scatter. K=FF=4096.
// EXACT R6 plateau config (106.8us; 10 variants measured, all worse):
// BM=64 x BN=128, 4 waves x (32x64), single-buffered, 24 KiB LDS,
// m-fast grid (x=m 256 tiles, y=n 8).
__global__ __launch_bounds__(256, 4) void k_gemm2(const __hip_bfloat16* __restrict__ Act,
                                                  const __hip_bfloat16* __restrict__ Bt,
                                                  const float* __restrict__ bias,
                                                  const int* __restrict__ idx,
                                                  float* __restrict__ out,
                                                  const int* __restrict__ cnt) {
  const int Mc = *cnt;
  const int m0 = blockIdx.x * 64;
  if (m0 >= Mc) return;
  const int n0 = blockIdx.y * 128;

  __shared__ __hip_bfloat16 lA[64 * 64];   // 8 KiB
  __shared__ __hip_bfloat16 lB[128 * 64];  // 16 KiB

  const int tid = threadIdx.x;
  const int wave = tid >> 6, lane = tid & 63;
  const int wr = (wave >> 1) * 32, wc = (wave & 1) * 64;
  const int fm = lane & 15, quad = lane >> 4;
  const int srow = (lane >> 3);
  const int sg   = ((lane & 7) ^ srow) * 8;

  f32x4 acc[2][4] = {};

  const __hip_bfloat16* gA = Act + (size_t)(m0 + wave * 16 + srow) * FF + sg;
  const __hip_bfloat16* gB = Bt  + (size_t)(n0 + wave * 32 + srow) * FF + sg;
  char* dA = (char*)lA + wave * 2048;
  char* dB = (char*)lB + wave * 4096;

  for (int kt = 0; kt < FF; kt += 64) {
    __syncthreads();
#pragma unroll
    for (int c = 0; c < 2; ++c)
      gload_lds16(gA + (size_t)(c * 8) * FF + kt, dA + c * 1024);
#pragma unroll
    for (int c = 0; c < 4; ++c)
      gload_lds16(gB + (size_t)(c * 8) * FF + kt, dB + c * 1024);
    __syncthreads();
#pragma unroll
    for (int ks = 0; ks < 2; ++ks) {
      bf16x8 af[2], bb[4];
#pragma unroll
      for (int i = 0; i < 2; ++i)
        af[i] = *(const bf16x8*)&lA[(wr + i * 16 + fm) * 64 + (((ks * 4 + quad) ^ (fm & 7)) * 8)];
#pragma unroll
      for (int j = 0; j < 4; ++j)
        bb[j] = *(const bf16x8*)&lB[(wc + j * 16 + fm) * 64 + (((ks * 4 + quad) ^ (fm & 7)) * 8)];
#pragma unroll
      for (int i = 0; i < 2; ++i)
#pragma unroll
        for (int j = 0; j < 4; ++j)
          acc[i][j] = __builtin_amdgcn_mfma_f32_16x16x32_bf16(af[i], bb[j], acc[i][j], 0, 0, 0);
    }
  }

#pragma unroll
  for (int i = 0; i < 2; ++i) {
#pragma unroll
    for (int r = 0; r < 4; ++r) {
      const int m = m0 + wr + i * 16 + quad * 4 + r;
      if (m < Mc) {
        const int t = idx[m];
        float* orow = out + (size_t)t * HID + n0 + wc + fm;
#pragma unroll
        for (int j = 0; j < 4; ++j)
          orow[j * 16] = acc[i][j][r] + bias[n0 + wc + j * 16 + fm];
      }
    }
  }
}

// ---------------- launch ----------------
extern "C" void kernel_launch(void* const* d_in, const int* in_sizes, int n_in,
                              void* d_out, int out_size, void* d_ws, size_t ws_size,
                              hipStream_t stream) {
  const float* h   = (const float*)d_in[0];
  const float* Wg  = (const float*)d_in[3];
  const float* bg  = (const float*)d_in[4];
  const float* W1  = (const float*)d_in[5];
  const float* b1  = (const float*)d_in[6];
  const float* W2  = (const float*)d_in[7];
  const float* b2  = (const float*)d_in[8];
  const int*  labels = (const int*)d_in[9];
  float* out = (float*)d_out;

  char* ws = (char*)d_ws;
  int* cnt            = (int*)(ws + 0);
  int* idx            = (int*)(ws + 1024);
  __hip_bfloat16* W1t = (__hip_bfloat16*)(ws + (1u  << 17));   // [FF][HID]
  __hip_bfloat16* W2t = (__hip_bfloat16*)(ws + (16u << 20));   // [HID][FF]
  __hip_bfloat16* A   = (__hip_bfloat16*)(ws + (32u << 20));   // [TOK][HID]
  __hip_bfloat16* Act = (__hip_bfloat16*)(ws + (64ull << 20)); // [TOK][FF]

  hipMemsetAsync(cnt, 0, 4, stream);
  k_pre<<<NBT1 + TOK / GTOK, 256, 0, stream>>>(W1, W1t, h, Wg, bg, labels,
                                               out, A, idx, cnt);
  k_gemm1<<<NBT2 + (TOK / 128) * (FF / 128), 256, 0, stream>>>(A, W1t, b1, Act,
                                                               cnt, W2, W2t);
  k_gemm2<<<dim3(TOK / 64, HID / 128), 256, 0, stream>>>(Act, W2t, b2, idx, out, cnt);
}